// Round 1
// baseline (865.014 us; speedup 1.0000x reference)
//
#include <hip/hip_runtime.h>
#include <math.h>

#define N_PRED   2000000
#define N_OBS    1000000
#define RASU     200000
#define N_IMAGES 2000
#define HMAX     60
#define GRID_    121
#define MC       32
#define NPART    64
#define LOG2PI_D 1.8378770664093453

// ---------------- Kernel A: softplus(q_raw_scale), Z = qloc + qs*eps (transposed), KL ----
__global__ __launch_bounds__(256)
void prep_kernel(const float* __restrict__ qloc, const float* __restrict__ qraw,
                 const float* __restrict__ eps, float* __restrict__ Qs,
                 float* __restrict__ Z, double* __restrict__ accums, int useZ)
{
    int r = blockIdx.x * 256 + threadIdx.x;
    double klv = 0.0;
    if (r < RASU) {
        float x  = qraw[r];
        float sp = (x > 0.f) ? (x + log1pf(expf(-x))) : log1pf(expf(x));
        float qs = sp + 1e-6f;
        float ql = qloc[r];
        Qs[r] = qs;
        klv = (double)(-logf(qs) + 0.5f * (qs * qs + ql * ql) - 0.5f);
        if (useZ) {
            float4* Zp = (float4*)Z;
#pragma unroll
            for (int c = 0; c < 8; c++) {
                float4 v;
                v.x = fmaf(qs, eps[(size_t)(4 * c + 0) * RASU + r], ql);
                v.y = fmaf(qs, eps[(size_t)(4 * c + 1) * RASU + r], ql);
                v.z = fmaf(qs, eps[(size_t)(4 * c + 2) * RASU + r], ql);
                v.w = fmaf(qs, eps[(size_t)(4 * c + 3) * RASU + r], ql);
                Zp[(size_t)r * 8 + c] = v;
            }
        }
    }
    // wave-level reduce of KL, then one atomic per wave
#pragma unroll
    for (int off = 32; off; off >>= 1) klv += __shfl_down(klv, off);
    if ((threadIdx.x & 63) == 0) atomicAdd(&accums[0], klv);
}

// ---------------- Kernel C: one thread per observation -------------------------------
template <int USEZ>
__global__ __launch_bounds__(256)
void obs_kernel(const int* __restrict__ hkl, const float* __restrict__ I,
                const float* __restrict__ SigI, const int* __restrict__ image_id,
                const float* __restrict__ metadata, const int* __restrict__ asu,
                const float* __restrict__ qloc, const float* __restrict__ Qs,
                const float* __restrict__ Z, const float* __restrict__ eps,
                const float* __restrict__ sw, const float* __restrict__ sbp,
                const float* __restrict__ ibias, double* __restrict__ partial)
{
    int o = blockIdx.x * 256 + threadIdx.x;
    if (o >= N_OBS) return;

    float w[9];
#pragma unroll
    for (int j = 0; j < 9; j++) w[j] = sw[j];
    float sb = sbp[0];

    float Iv = I[o], Sv = SigI[o];
    float inv  = 1.0f / Sv;
    float logs = logf(Sv);

    int p0 = 2 * o;
    int ia0 = image_id[p0], ia1 = image_id[p0 + 1];
    int img = ia1;  // numpy last-write-wins scatter: pred 2o+1 wins

    // op-independent per-prediction base of the log-scale
    float basep[2];
    {
        const float* m0 = metadata + (size_t)p0 * 5;
#pragma unroll
        for (int j = 0; j < 2; j++) {
            const float* m = m0 + 5 * j;
            float b = w[2] * Iv;
            b = fmaf(w[3], Sv, b);
#pragma unroll
            for (int k = 0; k < 5; k++) b = fmaf(w[4 + k], m[k], b);
            basep[j] = b + sb + ibias[j == 0 ? ia0 : ia1];
        }
    }

    int h[2][3];
#pragma unroll
    for (int j = 0; j < 6; j++) ((int*)h)[j] = hkl[(size_t)p0 * 3 + j];

    int   r[3][2];
    float s[3][2];
    float qv[3][2], qsv[3][2];   // only used by the !USEZ fallback
#pragma unroll
    for (int op = 0; op < 3; op++) {
#pragma unroll
        for (int j = 0; j < 2; j++) {
            int x, y, z;
            if (op == 0)      { x =  h[j][0]; y =  h[j][1]; z =  h[j][2]; }
            else if (op == 1) { x = -h[j][0]; y = -h[j][1]; z = -h[j][2]; }
            else              { x =  h[j][1]; y =  h[j][0]; z = -h[j][2]; }
            int flat = ((x + HMAX) * GRID_ + (y + HMAX)) * GRID_ + (z + HMAX);
            int rr = asu[flat];
            r[op][j] = rr;
            float q0 = qloc[rr], q1 = Qs[rr];
            if (!USEZ) { qv[op][j] = q0; qsv[op][j] = q1; }
            s[op][j] = expf(basep[j] + fmaf(w[0], q0, w[1] * q1));
        }
    }

    float acc[3] = {0.f, 0.f, 0.f};
    if (USEZ) {
        const float4* Zp = (const float4*)Z;
#pragma unroll
        for (int c = 0; c < 8; c++) {
#pragma unroll
            for (int op = 0; op < 3; op++) {
                float4 a = Zp[(size_t)r[op][0] * 8 + c];
                float4 b = Zp[(size_t)r[op][1] * 8 + c];
                float s0 = s[op][0], s1 = s[op][1];
                float t;
                t = (fmaf(b.x, s1, a.x * s0) - Iv) * inv; acc[op] = fmaf(t, t, acc[op]);
                t = (fmaf(b.y, s1, a.y * s0) - Iv) * inv; acc[op] = fmaf(t, t, acc[op]);
                t = (fmaf(b.z, s1, a.z * s0) - Iv) * inv; acc[op] = fmaf(t, t, acc[op]);
                t = (fmaf(b.w, s1, a.w * s0) - Iv) * inv; acc[op] = fmaf(t, t, acc[op]);
            }
        }
    } else {
        for (int mc = 0; mc < MC; mc++) {
            const float* ep = eps + (size_t)mc * RASU;
#pragma unroll
            for (int op = 0; op < 3; op++) {
                float z0 = fmaf(qsv[op][0], ep[r[op][0]], qv[op][0]);
                float z1 = fmaf(qsv[op][1], ep[r[op][1]], qv[op][1]);
                float t = (fmaf(z1, s[op][1], z0 * s[op][0]) - Iv) * inv;
                acc[op] = fmaf(t, t, acc[op]);
            }
        }
    }

    double base_ll = -32.0 * ((double)logs + 0.5 * LOG2PI_D);
    int pidx = (int)(blockIdx.x & (NPART - 1));
    double* pp = partial + ((size_t)pidx * N_IMAGES + img) * 3;
#pragma unroll
    for (int op = 0; op < 3; op++) {
        double ll = -0.5 * (double)acc[op] + base_ll;
        atomicAdd(pp + op, ll);
    }
}

// ---------------- Kernel D: per-image reduce over partials, argmax --------------------
__global__ __launch_bounds__(256)
void img_kernel(const double* __restrict__ partial, double* __restrict__ accums,
                float* __restrict__ out)
{
    int i = blockIdx.x * 256 + threadIdx.x;
    if (i >= N_IMAGES) return;
    double l0 = 0, l1 = 0, l2 = 0;
    for (int p = 0; p < NPART; p++) {
        const double* q = partial + ((size_t)p * N_IMAGES + i) * 3;
        l0 += q[0]; l1 += q[1]; l2 += q[2];
    }
    const double ninv = 1.0 / (double)(MC * MC);
    l0 *= ninv; l1 *= ninv; l2 *= ninv;
    int idx = 0; double best = l0;
    if (l1 > best) { best = l1; idx = 1; }
    if (l2 > best) { best = l2; idx = 2; }
    out[1 + i] = (float)idx;
    atomicAdd(&accums[1], best);
}

// ---------------- Kernel E: final ELBO ------------------------------------------------
__global__ void final_kernel(const double* __restrict__ accums, float* __restrict__ out)
{
    double elbo = -(accums[1] / (double)N_IMAGES) + (accums[0] / (double)RASU);
    out[0] = (float)elbo;
}

extern "C" void kernel_launch(void* const* d_in, const int* in_sizes, int n_in,
                              void* d_out, int out_size, void* d_ws, size_t ws_size,
                              hipStream_t stream)
{
    const int*   hkl      = (const int*)  d_in[0];
    const float* I        = (const float*)d_in[1];
    const float* SigI     = (const float*)d_in[2];
    const int*   image_id = (const int*)  d_in[3];
    const float* metadata = (const float*)d_in[4];
    // d_in[5] harmonic_id: structurally arange//2, unused
    const int*   asu      = (const int*)  d_in[6];
    const float* qloc     = (const float*)d_in[7];
    const float* qraw     = (const float*)d_in[8];
    const float* eps      = (const float*)d_in[9];
    const float* sw       = (const float*)d_in[10];
    const float* sb       = (const float*)d_in[11];
    const float* ibias    = (const float*)d_in[12];
    float* out = (float*)d_out;

    char* ws = (char*)d_ws;
    size_t off = 0;
    double* partial = (double*)(ws + off); off += (size_t)NPART * N_IMAGES * 3 * sizeof(double);
    double* accums  = (double*)(ws + off); off += 2 * sizeof(double);
    float*  Qs      = (float*) (ws + off); off += (size_t)RASU * sizeof(float);
    off = (off + 15) & ~(size_t)15;
    float*  Z       = (float*) (ws + off);
    size_t zbytes   = (size_t)RASU * MC * sizeof(float);
    int useZ = (off + zbytes <= ws_size) ? 1 : 0;

    // zero partial bins + the two accumulators (contiguous)
    hipMemsetAsync(partial, 0, (size_t)NPART * N_IMAGES * 3 * sizeof(double) + 2 * sizeof(double), stream);

    prep_kernel<<<(RASU + 255) / 256, 256, 0, stream>>>(qloc, qraw, eps, Qs, Z, accums, useZ);

    int blocksC = (N_OBS + 255) / 256;
    if (useZ) {
        obs_kernel<1><<<blocksC, 256, 0, stream>>>(hkl, I, SigI, image_id, metadata, asu,
                                                   qloc, Qs, Z, eps, sw, sb, ibias, partial);
    } else {
        obs_kernel<0><<<blocksC, 256, 0, stream>>>(hkl, I, SigI, image_id, metadata, asu,
                                                   qloc, Qs, Z, eps, sw, sb, ibias, partial);
    }

    img_kernel<<<(N_IMAGES + 255) / 256, 256, 0, stream>>>(partial, accums, out);
    final_kernel<<<1, 1, 0, stream>>>(accums, out);
}